// Round 11
// baseline (3597.764 us; speedup 1.0000x reference)
//
#include <hip/hip_runtime.h>
#include <hip/hip_bf16.h>

#define T_STEPS 512
#define TS_US   65536         // ushorts per t-slot (128KB): 8 groups x 16 kt x 64 lanes x 8

typedef __attribute__((ext_vector_type(4))) float f32x4;
typedef __attribute__((ext_vector_type(8))) short s16x8;
typedef __attribute__((ext_vector_type(4))) unsigned int u32x4;

// ---------- helpers ----------
__device__ __forceinline__ unsigned short f2bf(float f){
  unsigned int u = __float_as_uint(f);
  unsigned int r = (u + 0x7fffu + ((u >> 16) & 1u)) >> 16;
  return (unsigned short)r;
}
__device__ __forceinline__ float ftanh(float x){
  x = fminf(fmaxf(x, -15.f), 15.f);
  float a = __expf(2.f * x);
  return (a - 1.f) * __builtin_amdgcn_rcpf(a + 1.f);
}
__device__ __forceinline__ s16x8 as_frag(u32x4 v){
  union { u32x4 u; s16x8 s; } c; c.u = v; return c.s;
}
__device__ __forceinline__ float bpermf(int byte_addr, float v){
  return __int_as_float(__builtin_amdgcn_ds_bpermute(byte_addr, __float_as_int(v)));
}

// ---------- pack x into per-group (16-row) MFMA A-fragment layout ----------
// layout chunks: [t][g(8)][kt(16)][lane(64)][8] bf16; row=lane&15, k=kt*32+(lane>>4)*8+e
__global__ void k_pack_x(const float* __restrict__ x, unsigned short* __restrict__ xp){
  int t = blockIdx.x >> 3, q = blockIdx.x & 7;
  __shared__ unsigned short xs[16*520];
  int tid = threadIdx.x;
  for (int qq = tid; qq < 1024; qq += 256){
    int rw = qq >> 6, k8 = qq & 63;
    const float* src = x + ((size_t)(q*16 + rw)*512 + t)*512 + k8*8;
    union { unsigned short u[8]; s16x8 v; } tmp;
#pragma unroll
    for (int e = 0; e < 8; e++) tmp.u[e] = f2bf(src[e]);
    *(s16x8*)&xs[rw*520 + k8*8] = tmp.v;
  }
  __syncthreads();
  for (int s = tid; s < 1024; s += 256){
    int kt = s >> 6, ln = s & 63;
    int rw2 = ln & 15, k0 = kt*32 + (ln >> 4)*8;
    s16x8 v = *(const s16x8*)&xs[rw2*520 + k0];
    ((s16x8*)xp)[(size_t)t*8192 + (q*16 + kt)*64 + ln] = v;
  }
}

// ---------- pack layer-1 weights: per-rank full-K B-fragments ----------
// wp chunks: [rank(128)][kt(32)][lane(64)][8]; tile col c=lane&15 -> j=c>>2,gt=c&3,
// zcol = gt*512 + rank*4 + j; k = kt*32 + ((lane>>4)&3)*8 + e (kt<16: Wi row k; else Wh row k-512)
__global__ void k_pack_w1(const float* __restrict__ Wi, const float* __restrict__ Wh,
                          const float* __restrict__ b, unsigned short* __restrict__ wp,
                          float* __restrict__ bias){
  int rank = blockIdx.x, tid = threadIdx.x;
  for (int idx = tid; idx < 2048; idx += 256){
    int kt = idx >> 6, lane = idx & 63;
    int cc = lane & 15, j = cc >> 2, gt = cc & 3;
    int zcol = gt*512 + rank*4 + j;
    int kb = kt*32 + ((lane >> 4) & 3)*8;
    union { unsigned short u[8]; s16x8 v; } tmp;
#pragma unroll
    for (int e = 0; e < 8; e++){
      int k = kb + e;
      float wv = (kt < 16) ? Wi[(size_t)k*2048 + zcol] : Wh[(size_t)(k-512)*2048 + zcol];
      tmp.u[e] = f2bf(wv);
    }
    ((s16x8*)wp)[(size_t)rank*2048 + idx] = tmp.v;
  }
  if (tid < 16){
    int j = (tid >> 2) & 3, gt = tid & 3;
    bias[rank*16 + tid] = b[gt*512 + rank*4 + j];
  }
}

// ---------- fold BN1 into Wi2, pack layer-2 weights, fused bias ----------
__global__ void k_fold2(const float* __restrict__ Wi2, const float* __restrict__ Wh2,
                        const float* __restrict__ b2, const float* __restrict__ gamma,
                        const float* __restrict__ beta, const float* __restrict__ stats,
                        unsigned short* __restrict__ wp, float* __restrict__ bias){
  __shared__ float a_s[512], c_s[512], red[256];
  int rank = blockIdx.x, tid = threadIdx.x;
  for (int k = tid; k < 512; k += 256){
    float sm = 0.f, sq = 0.f;
#pragma unroll
    for (int g = 0; g < 8; g++){ sm += stats[(k*8+g)*2]; sq += stats[(k*8+g)*2+1]; }
    float mean = sm * (1.f/65536.f);
    float var  = sq * (1.f/65536.f) - mean*mean;
    float rr = rsqrtf(fmaxf(var, 0.f) + 1e-5f);
    float a = rr * gamma[k];
    a_s[k] = a; c_s[k] = beta[k] - mean*a;
  }
  __syncthreads();
  for (int idx = tid; idx < 2048; idx += 256){
    int kt = idx >> 6, lane = idx & 63;
    int cc = lane & 15, j = cc >> 2, gt = cc & 3;
    int zcol = gt*512 + rank*4 + j;
    int kb = kt*32 + ((lane >> 4) & 3)*8;
    union { unsigned short u[8]; s16x8 v; } tmp;
#pragma unroll
    for (int e = 0; e < 8; e++){
      int k = kb + e;
      float wv = (kt < 16) ? a_s[k]*Wi2[(size_t)k*2048 + zcol]
                           : Wh2[(size_t)(k-512)*2048 + zcol];
      tmp.u[e] = f2bf(wv);
    }
    ((s16x8*)wp)[(size_t)rank*2048 + idx] = tmp.v;
  }
  // bias' = b2 + c_s @ Wi2 for this rank's 16 cols
  int colj = tid >> 4, part = tid & 15;
  int j = (colj >> 2) & 3, gt = colj & 3;
  int zcol = gt*512 + rank*4 + j;
  float s = 0.f;
  for (int k = part*32; k < part*32 + 32; k++) s += c_s[k]*Wi2[(size_t)k*2048 + zcol];
  red[tid] = s;
  __syncthreads();
  if (part == 0){
    float tot = b2[zcol];
#pragma unroll
    for (int q = 0; q < 16; q++) tot += red[colj*16 + q];
    bias[rank*16 + colj] = tot;
  }
}

__global__ void k_reset(int* f1, int* f2, int* x1, int* x2){
  int t = threadIdx.x;
  for (int i = t; i < 16384; i += 1024){ f1[i] = 0; f2[i] = 0; }
  for (int i = t; i < 2048; i += 1024){ x1[i] = 0; x2[i] = 0; }
}

__global__ void k_sentinel(float* out, int n, float v){
  int i = blockIdx.x * blockDim.x + threadIdx.x;
  if (i < n) out[i] = v;
}

// ---------- persistent LSTM scan: full-K-per-wave ranks ----------
// 256 blocks x 256 threads. g = blockIdx&7 (XCD-aligned group, 16 batch rows),
// bq = blockIdx>>3; rank = bq*4 + wave (128 ranks/group, 4 h-cols each).
// Each rank-wave holds the FULL K (32 B-frags, 128 VGPR): its MFMA output is the
// COMPLETE z for its 16-col tile -> no LDS zones, no cross-wave reduction, gates
// in-wave via ds_bpermute (4-lane clusters c=4j+g). x-frags (identical for all
// ranks of a group) staged in LDS once per block, double-buffered, 2 ahead.
// Sync: per-rank flag dword; fastp: plain store -> nt-load poll through XCD L2
// (r7/r9-proven); producer vmcnt(0) ack orders h-stores before flag. Fallback:
// agent-relaxed atomics (r8-proven). All valves bounded.
template<int LAYER>
__global__ __launch_bounds__(256, 1)
void k_scan(const unsigned short* __restrict__ xin, unsigned short* __restrict__ hex,
            const unsigned short* __restrict__ wp, const float* __restrict__ bias,
            int* __restrict__ flags, int* __restrict__ xmap, float* __restrict__ aux){
  __shared__ __align__(16) unsigned short xs[2][8192];
  __shared__ int s_mode;
  int g = blockIdx.x & 7, bq = blockIdx.x >> 3;
  int tid = threadIdx.x, w = tid >> 6, lane = tid & 63;
  int rank = bq*4 + w;

  // full-K weight fragments -> registers (volatile: load exactly once)
  const volatile s16x8* wpv = (const volatile s16x8*)((const s16x8*)wp + (size_t)rank*2048);
  s16x8 B[32];
#pragma unroll
  for (int ki = 0; ki < 32; ki++) B[ki] = wpv[ki*64 + lane];
  float bv = bias[rank*16 + (lane & 15)];

  // ---- stage 1: XCD uniformity handshake ----
  int myx;
  asm volatile("s_getreg_b32 %0, hwreg(HW_REG_XCC_ID)" : "=s"(myx));
  if (tid == 0)
    __hip_atomic_store(&xmap[g*32 + bq], (myx & 0xff) + 1, __ATOMIC_RELAXED, __HIP_MEMORY_SCOPE_AGENT);
  int xv, hb = 0;
  for (;;){
    xv = __hip_atomic_load(&xmap[g*32 + (lane & 31)], __ATOMIC_RELAXED, __HIP_MEMORY_SCOPE_AGENT);
    if (__all(xv != 0)) break;
    __builtin_amdgcn_s_sleep(2);
    if (++hb > (1<<16)) break;
  }
  int xv0 = __builtin_amdgcn_readfirstlane(xv);
  bool fastp = __all(xv != 0 && xv == xv0) != 0;

  // ---- stage 2: nt-visibility probe (plain store -> nt load) ----
  int ntok = 0;
  if (fastp){
    if (tid == 0)
      __hip_atomic_store(&xmap[512 + g*32 + bq], bq + 1, __ATOMIC_RELAXED, __HIP_MEMORY_SCOPE_WORKGROUP);
    if (w == 0){
      asm volatile("s_waitcnt vmcnt(0)" ::: "memory");
      int tries = 0;
      for (;;){
        asm volatile("" ::: "memory");
        int pv = __builtin_nontemporal_load(&xmap[512 + g*32 + (lane & 31)]);
        if (__all(pv != 0)){ ntok = 1; break; }
        __builtin_amdgcn_s_sleep(1);
        if (++tries > 2048) break;
      }
    }
  }
  // ---- stage 3: group consensus vote ----
  if (tid == 0)
    __hip_atomic_store(&xmap[1024 + g*32 + bq], ntok ? 2 : 1, __ATOMIC_RELAXED, __HIP_MEMORY_SCOPE_AGENT);
  if (w == 0){
    int allfast = 0, vb = 0;
    for (;;){
      int v = __hip_atomic_load(&xmap[1024 + g*32 + (lane & 31)], __ATOMIC_RELAXED, __HIP_MEMORY_SCOPE_AGENT);
      if (__all(v != 0)){ allfast = (__all(v == 2) ? 1 : 0); break; }
      __builtin_amdgcn_s_sleep(2);
      if (++vb > (1<<18)){ allfast = 0; break; }
    }
    if (tid == 0) s_mode = allfast;
  }
  __syncthreads();
  bool dpoll = (s_mode != 0);   // implies fastp

  // lane constants
  int rq = lane >> 4, cc = lane & 15, j = cc >> 2, gt = cc & 3;
  bool isg = (gt == 2);
  int row_sel = rq*4 + gt;
  int kk = rank*4 + j;
  int ktp = kk >> 5, g3 = (kk >> 3) & 3, ep = kk & 7;
  size_t pub_chunk = (size_t)g*1024 + (size_t)ktp*64 + (row_sel + 16*g3);
  int bpa = (lane & ~3) * 4;    // bpermute byte base of this 4-lane cluster

  float cst[4] = {0.f, 0.f, 0.f, 0.f};
  float s1 = 0.f, s2 = 0.f;

  const u32x4* xc  = (const u32x4*)xin;
  const u32x4* hc4 = (const u32x4*)hex;
  unsigned int* hvw = (unsigned int*)hex;
  int* myflag = flags + (g*128 + rank)*16;
  const int* pf0 = flags + (g*128 + lane)*16;
  const int* pf1 = flags + (g*128 + 64 + lane)*16;

  // prologue: stage x(0), x(1) into LDS (each wave its 4-ktile quarter)
  {
    u32x4 r0[4], r1[4];
#pragma unroll
    for (int i = 0; i < 4; i++) r0[i] = xc[(size_t)g*1024 + w*256 + i*64 + lane];
#pragma unroll
    for (int i = 0; i < 4; i++) r1[i] = xc[(size_t)8192 + g*1024 + w*256 + i*64 + lane];
#pragma unroll
    for (int i = 0; i < 4; i++) *(u32x4*)&xs[0][(w*256 + i*64 + lane)*8] = r0[i];
#pragma unroll
    for (int i = 0; i < 4; i++) *(u32x4*)&xs[1][(w*256 + i*64 + lane)*8] = r1[i];
  }
  __syncthreads();

  for (int t = 0; t < T_STEPS; t++){
    f32x4 acc[4];
#pragma unroll
    for (int n = 0; n < 4; n++) acc[n] = (f32x4){0.f,0.f,0.f,0.f};
    // X phase from LDS (full K=512 of x)
#pragma unroll
    for (int kt = 0; kt < 16; kt++){
      s16x8 a = *(const s16x8*)&xs[t & 1][(kt*64 + lane)*8];
      acc[kt & 3] = __builtin_amdgcn_mfma_f32_16x16x32_bf16(a, B[kt], acc[kt & 3], 0, 0, 0);
    }
    __syncthreads();                    // all waves done reading xs[t&1]
    // stage loads for t+2 (into regs; written to xs[t&1] after the poll)
    u32x4 xr[4];
    bool do_stage = (t + 2 < T_STEPS);
    if (do_stage){
      const u32x4* sp = xc + ((size_t)(t+2)*8192 + g*1024 + w*256 + lane);
#pragma unroll
      for (int i = 0; i < 4; i++) xr[i] = sp[i*64];
    }
    if (t > 0){
      // poll 128 per-rank flags (2 nt dwords per lane)
      int bail = 0;
      if (dpoll){
        for (;;){
          int f0 = __builtin_nontemporal_load(pf0);
          int f1 = __builtin_nontemporal_load(pf1);
          if (__all(f0 >= t && f1 >= t)) break;
          __builtin_amdgcn_s_sleep(1);
          if (++bail > (1<<13)) break;
        }
      } else {
        for (;;){
          int f0 = __hip_atomic_load(pf0, __ATOMIC_RELAXED, __HIP_MEMORY_SCOPE_AGENT);
          int f1 = __hip_atomic_load(pf1, __ATOMIC_RELAXED, __HIP_MEMORY_SCOPE_AGENT);
          if (__all(f0 >= t && f1 >= t)) break;
          __builtin_amdgcn_s_sleep(2);
          if (++bail > (1<<13)) break;
        }
      }
      asm volatile("" ::: "memory");
      // h loads (full K=512 of h) + MFMA
      const u32x4* hp = hc4 + ((size_t)(t-1)*8192 + g*1024 + lane);
#pragma unroll
      for (int kt = 0; kt < 16; kt++){
        u32x4 hv = dpoll ? __builtin_nontemporal_load(hp + kt*64) : hp[kt*64];
        acc[kt & 3] = __builtin_amdgcn_mfma_f32_16x16x32_bf16(as_frag(hv), B[16 + kt], acc[kt & 3], 0, 0, 0);
      }
    }
    // stage write t+2 into freed buffer
    if (do_stage){
#pragma unroll
      for (int i = 0; i < 4; i++) *(u32x4*)&xs[t & 1][(w*256 + i*64 + lane)*8] = xr[i];
    }
    // complete z (in-wave), activations
    f32x4 z = acc[0] + acc[1] + acc[2] + acc[3];
    float av[4], hloc[4];
#pragma unroll
    for (int i = 0; i < 4; i++){
      float zb = z[i] + bv;
      float xx = isg ? zb : 0.5f*zb;
      float tt = ftanh(xx);
      av[i] = isg ? tt : (0.5f*tt + 0.5f);   // sigmoid via tanh identity
    }
    // gather i,f,g,o within the 4-lane cluster; update c; compute h
#pragma unroll
    for (int i = 0; i < 4; i++){
      float ai = bpermf(bpa,      av[i]);
      float af = bpermf(bpa + 4,  av[i]);
      float ag = bpermf(bpa + 8,  av[i]);
      float ao = bpermf(bpa + 12, av[i]);
      cst[i] = af*cst[i] + ai*ag;
      hloc[i] = ao * ftanh(cst[i]);
      if (LAYER == 1){ s1 += hloc[i]; s2 += hloc[i]*hloc[i]; }
    }
    // publish: lane (rq, 4j+gt) owns (row rq*4+gt, col j); pair cols via shfl_xor(4)
    float hsel = (gt & 2) ? ((gt & 1) ? hloc[3] : hloc[2])
                          : ((gt & 1) ? hloc[1] : hloc[0]);
    unsigned hbv = f2bf(hsel);
    unsigned pbv = (unsigned)__shfl_xor((int)hbv, 4);
    if ((j & 1) == 0){
      unsigned dw = hbv | (pbv << 16);
      unsigned int* dst = hvw + (size_t)t*32768 + pub_chunk*4 + (ep >> 1);
      if (fastp) *dst = dw;
      else __hip_atomic_store(dst, dw, __ATOMIC_RELAXED, __HIP_MEMORY_SCOPE_AGENT);
    }
    if (LAYER == 2 && t == T_STEPS-1)
      aux[(size_t)(g*16 + row_sel)*512 + rank*4 + j] = hsel;
    asm volatile("s_waitcnt vmcnt(0)" ::: "memory");   // h stores ordered before flag
    if (lane == 0){
      if (fastp) *(volatile int*)myflag = t + 1;
      else __hip_atomic_store(myflag, t + 1, __ATOMIC_RELAXED, __HIP_MEMORY_SCOPE_AGENT);
    }
  }

  if (LAYER == 1){
    // reduce stats over 16 rows (4 rq-quadrants hold disjoint rows)
    s1 += __shfl_xor(s1, 16); s2 += __shfl_xor(s2, 16);
    s1 += __shfl_xor(s1, 32); s2 += __shfl_xor(s2, 32);
    if (lane < 16 && gt == 0){
      int ch = rank*4 + j;
      aux[(ch*8 + g)*2]     = s1;
      aux[(ch*8 + g)*2 + 1] = s2;
    }
  }
}

// ---------- BN2 + dense head ----------
__global__ __launch_bounds__(512)
void k_epilogue(const float* __restrict__ h2,
                const float* __restrict__ g2, const float* __restrict__ be2,
                const float* __restrict__ Wd1, const float* __restrict__ bd1,
                const float* __restrict__ Wd2, const float* __restrict__ bd2,
                float* __restrict__ out){
  __shared__ float mu[512], rs[512], bb[512];
  __shared__ float t16[128*16];
  int tid = threadIdx.x;
  {
    float s = 0.f, qq = 0.f;
    for (int r = 0; r < 128; r++){ float v = h2[r*512 + tid]; s += v; qq += v*v; }
    float m = s * (1.f/128.f);
    float var = qq * (1.f/128.f) - m*m;
    mu[tid] = m;
    rs[tid] = rsqrtf(fmaxf(var,0.f) + 1e-5f) * g2[tid];
    bb[tid] = be2[tid];
  }
  __syncthreads();
  for (int task = tid; task < 2048; task += 512){
    int b = task >> 4, u = task & 15;
    float acc = bd1[u];
    for (int k = 0; k < 512; k++){
      float hn = (h2[b*512 + k] - mu[k]) * rs[k] + bb[k];
      acc += hn * Wd1[k*16 + u];
    }
    t16[task] = tanhf(acc);
  }
  __syncthreads();
  if (tid < 128){
    float acc = bd2[0];
#pragma unroll
    for (int u = 0; u < 16; u++) acc += t16[tid*16 + u] * Wd2[u];
    out[tid] = acc;
  }
}

extern "C" void kernel_launch(void* const* d_in, const int* in_sizes, int n_in,
                              void* d_out, int out_size, void* d_ws, size_t ws_size,
                              hipStream_t stream){
  const float* x    = (const float*)d_in[0];
  const float* Wi1  = (const float*)d_in[1];
  const float* Wh1  = (const float*)d_in[2];
  const float* b1   = (const float*)d_in[3];
  const float* Wi2  = (const float*)d_in[4];
  const float* Wh2  = (const float*)d_in[5];
  const float* b2   = (const float*)d_in[6];
  const float* g1   = (const float*)d_in[7];
  const float* be1  = (const float*)d_in[8];
  const float* g2   = (const float*)d_in[9];
  const float* be2  = (const float*)d_in[10];
  const float* Wd1  = (const float*)d_in[11];
  const float* bd1  = (const float*)d_in[12];
  const float* Wd2  = (const float*)d_in[13];
  const float* bd2  = (const float*)d_in[14];
  float* out = (float*)d_out;

  char* ws = (char*)d_ws;
  size_t off = 0;
  auto alloc = [&](size_t bytes)->void*{
    void* pp = ws + off; off += (bytes + 255) & ~(size_t)255; return pp;
  };
  unsigned short* xpacked = (unsigned short*)alloc((size_t)512*TS_US*2);  // 64 MiB
  unsigned short* S       = (unsigned short*)alloc((size_t)514*TS_US*2);  // 64.25 MiB
  unsigned short* w1p     = (unsigned short*)alloc((size_t)128*32*64*8*2);
  unsigned short* w2p     = (unsigned short*)alloc((size_t)128*32*64*8*2);
  float* bias1  = (float*)alloc(2048*4);
  float* bias2  = (float*)alloc(2048*4);
  float* stats1 = (float*)alloc((size_t)512*8*2*4);
  int*   flags1 = (int*)alloc(16384*4);
  int*   flags2 = (int*)alloc(16384*4);
  int*   xmap1  = (int*)alloc(2048*4);
  int*   xmap2  = (int*)alloc(2048*4);
  float* h2last = (float*)alloc((size_t)128*512*4);

  if (off > ws_size){
    k_sentinel<<<1, 256, 0, stream>>>(out, out_size, (float)(ws_size >> 20));
    return;
  }

  unsigned short* S2 = S + (size_t)2*TS_US;

  k_reset<<<1, 1024, 0, stream>>>(flags1, flags2, xmap1, xmap2);
  k_pack_x<<<4096, 256, 0, stream>>>(x, xpacked);
  k_pack_w1<<<128, 256, 0, stream>>>(Wi1, Wh1, b1, w1p, bias1);
  k_scan<1><<<256, 256, 0, stream>>>(xpacked, S2, w1p, bias1, flags1, xmap1, stats1);
  k_fold2<<<128, 256, 0, stream>>>(Wi2, Wh2, b2, g1, be1, stats1, w2p, bias2);
  k_scan<2><<<256, 256, 0, stream>>>(S2, xpacked, w2p, bias2, flags2, xmap2, h2last);
  k_epilogue<<<1, 512, 0, stream>>>(h2last, g2, be2, Wd1, bd1, Wd2, bd2, out);
}

// Round 12
// 2186.280 us; speedup vs baseline: 1.6456x; 1.6456x over previous
//
#include <hip/hip_runtime.h>
#include <hip/hip_bf16.h>

#define T_STEPS 512
#define TS_US   65536         // ushorts per t-slot (128KB) for x and h buffers
#define SENT    0x7FC07FC0u   // bf16 NaN pair: h can never equal this

typedef __attribute__((ext_vector_type(4))) float f32x4;
typedef __attribute__((ext_vector_type(8))) short s16x8;
typedef __attribute__((ext_vector_type(4))) unsigned int u32x4;

// ---------- helpers ----------
__device__ __forceinline__ unsigned short f2bf(float f){
  unsigned int u = __float_as_uint(f);
  unsigned int r = (u + 0x7fffu + ((u >> 16) & 1u)) >> 16;
  return (unsigned short)r;
}
__device__ __forceinline__ float fsig(float x){
  return __builtin_amdgcn_rcpf(1.f + __expf(-x));
}
__device__ __forceinline__ float ftanh(float x){
  x = fminf(fmaxf(x, -15.f), 15.f);
  float a = __expf(2.f * x);
  return (a - 1.f) * __builtin_amdgcn_rcpf(a + 1.f);
}
__device__ __forceinline__ s16x8 as_frag(u32x4 v){
  union { u32x4 u; s16x8 s; } c; c.u = v; return c.s;
}

// ---------- pack x into 16-row (q-group) MFMA A-fragment layout ----------
__global__ void k_pack_x(const float* __restrict__ x, unsigned short* __restrict__ xp){
  int t = blockIdx.x >> 3, q = blockIdx.x & 7;
  __shared__ unsigned short xs[16*520];
  int tid = threadIdx.x;
  for (int qq = tid; qq < 1024; qq += 256){
    int rw = qq >> 6, k8 = qq & 63;
    const float* src = x + ((size_t)(q*16 + rw)*512 + t)*512 + k8*8;
    union { unsigned short u[8]; s16x8 v; } tmp;
#pragma unroll
    for (int e = 0; e < 8; e++) tmp.u[e] = f2bf(src[e]);
    *(s16x8*)&xs[rw*520 + k8*8] = tmp.v;
  }
  __syncthreads();
  for (int s = tid; s < 1024; s += 256){
    int kt = s >> 6, ln = s & 63;
    int rw2 = ln & 15, k0 = kt*32 + (ln >> 4)*8;
    s16x8 v = *(const s16x8*)&xs[rw2*520 + k0];
    ((s16x8*)xp)[(size_t)t*8192 + (q*16 + kt)*64 + ln] = v;
  }
}

// ---------- pack layer-1 weights into B-fragment layout ----------
__global__ void k_pack_w1(const float* __restrict__ Wi, const float* __restrict__ Wh,
                          const float* __restrict__ b, unsigned short* __restrict__ wp,
                          float* __restrict__ bias){
  int r = blockIdx.x, tid = threadIdx.x;
  int lane = tid & 63, u0 = tid >> 6;
  for (int ch = u0; ch < 128; ch += 4){
    int kt = ch >> 2, n = ch & 3;
    int col = n*512 + r*16 + (lane & 15);
    int kb = kt*32 + (lane >> 4)*8;
    union { unsigned short u[8]; s16x8 v; } tmp;
#pragma unroll
    for (int e = 0; e < 8; e++){
      int k = kb + e;
      float wv = (kt < 16) ? Wi[(size_t)k*2048 + col] : Wh[(size_t)(k-512)*2048 + col];
      tmp.u[e] = f2bf(wv);
    }
    ((s16x8*)wp)[((size_t)r*128 + ch)*64 + lane] = tmp.v;
  }
  if (tid < 64) bias[r*64 + tid] = b[(tid >> 4)*512 + r*16 + (tid & 15)];
}

// ---------- fold BN1 into Wi2, pack layer-2 weights, fused bias ----------
__global__ void k_fold2(const float* __restrict__ Wi2, const float* __restrict__ Wh2,
                        const float* __restrict__ b2, const float* __restrict__ gamma,
                        const float* __restrict__ beta, const float* __restrict__ stats,
                        unsigned short* __restrict__ wp, float* __restrict__ bias){
  __shared__ float a_s[512], c_s[512], red[256];
  int r = blockIdx.x, tid = threadIdx.x;
  for (int k = tid; k < 512; k += 256){
    float sm = 0.f, sq = 0.f;
#pragma unroll
    for (int g = 0; g < 16; g++){ sm += stats[(k*16+g)*2]; sq += stats[(k*16+g)*2+1]; }
    float mean = sm * (1.f/65536.f);
    float var  = sq * (1.f/65536.f) - mean*mean;
    float rr = rsqrtf(fmaxf(var, 0.f) + 1e-5f);
    float a = rr * gamma[k];
    a_s[k] = a; c_s[k] = beta[k] - mean*a;
  }
  __syncthreads();
  int lane = tid & 63, u0 = tid >> 6;
  for (int ch = u0; ch < 128; ch += 4){
    int kt = ch >> 2, n = ch & 3;
    int col = n*512 + r*16 + (lane & 15);
    int kb = kt*32 + (lane >> 4)*8;
    union { unsigned short u[8]; s16x8 v; } tmp;
#pragma unroll
    for (int e = 0; e < 8; e++){
      int k = kb + e;
      float wv = (kt < 16) ? a_s[k]*Wi2[(size_t)k*2048 + col]
                           : Wh2[(size_t)(k-512)*2048 + col];
      tmp.u[e] = f2bf(wv);
    }
    ((s16x8*)wp)[((size_t)r*128 + ch)*64 + lane] = tmp.v;
  }
  int colj = tid >> 2, part = tid & 3;
  int n = colj >> 4, cl = colj & 15;
  int col = n*512 + r*16 + cl;
  float s = 0.f;
  for (int k = part*128; k < part*128 + 128; k++) s += c_s[k]*Wi2[(size_t)k*2048 + col];
  red[tid] = s;
  __syncthreads();
  if (part == 0)
    bias[r*64 + colj] = b2[col] + red[tid] + red[tid+1] + red[tid+2] + red[tid+3];
}

__global__ void k_reset(int* f1, int* f2, int* x1, int* x2){
  int t = threadIdx.x;
  for (int i = t; i < 8192; i += 1024){ f1[i] = 0; f2[i] = 0; }
  for (int i = t; i < 2048; i += 1024){ x1[i] = 0; x2[i] = 0; }
}

// fill a region with the bf16-NaN sentinel (n in uint4 units)
__global__ void k_fill(unsigned int* __restrict__ p, long n){
  u32x4 v = {SENT, SENT, SENT, SENT};
  u32x4* q = (u32x4*)p;
  long i = (long)blockIdx.x*blockDim.x + threadIdx.x;
  long stride = (long)gridDim.x*blockDim.x;
  for (; i < n; i += stride) q[i] = v;
}

__global__ void k_sentinel(float* out, int n, float v){
  int i = blockIdx.x * blockDim.x + threadIdx.x;
  if (i < n) out[i] = v;
}

// ---------- persistent group-local LSTM scan (r9 + speculative split poll) ---
// 512 blocks x 256 threads. 16 groups x 8 batch rows; gg = blockIdx&15,
// r = blockIdx>>4 (group's 32 ranks share one XCD; 2 groups/XCD, 2 blocks/CU).
// DATAPOLL (r9-proven): h-exchange slots write-once, NaN-sentinel pre-filled;
// consumers poll the h data itself with nt-loads. NEW in r12:
//  (1) speculative first poll issued BEFORE the X-phase (detect cost ~0 when
//      the producer finished during our gate tail);
//  (2) split validation: chunks 0/1 validated -> 8 MFMAs run while 2/3 may
//      still be in flight -> validate 2/3 -> remaining 8 MFMAs;
//  (3) hot spin (no s_sleep), bounded bail; memory clobber inside re-poll
//      loops prevents LICM hoisting of the nt loads.
// Fallback (probe/vote fails): round-8 flag mechanism, bit-exact.
template<int LAYER>
__global__ __launch_bounds__(256, 2)
void k_scan(const unsigned short* __restrict__ xin, unsigned short* __restrict__ hex,
            const unsigned short* __restrict__ wp, const float* __restrict__ bias,
            int* __restrict__ flags, int* __restrict__ xmap, float* __restrict__ aux){
  __shared__ __align__(16) float zs[2][4*64*20];
  __shared__ float blds[64];
  __shared__ int s_mode;
  int gg = blockIdx.x & 15, r = blockIdx.x >> 4;
  int q = gg >> 1, odd = gg & 1;
  int tid = threadIdx.x, w = tid >> 6, lane = tid & 63;

  // weight fragments -> registers/AGPRs (volatile: load exactly once)
  const volatile s16x8* wpv = (const volatile s16x8*)((const s16x8*)wp + (size_t)r*128*64);
  s16x8 B[8][4];
#pragma unroll
  for (int ki = 0; ki < 8; ki++){
    int kt = (ki < 4) ? (4*w + ki) : (12 + 4*w + ki);
#pragma unroll
    for (int n = 0; n < 4; n++)
      B[ki][n] = wpv[((size_t)kt*4 + n)*64 + lane];
  }
  if (tid < 64) blds[tid] = bias[r*64 + tid];

  // ---- stage 1: XCD uniformity handshake ----
  int myx;
  asm volatile("s_getreg_b32 %0, hwreg(HW_REG_XCC_ID)" : "=s"(myx));
  if (tid == 0)
    __hip_atomic_store(&xmap[gg*32 + r], (myx & 0xff) + 1, __ATOMIC_RELAXED, __HIP_MEMORY_SCOPE_AGENT);
  int xv, hb = 0;
  for (;;){
    xv = __hip_atomic_load(&xmap[gg*32 + (lane & 31)], __ATOMIC_RELAXED, __HIP_MEMORY_SCOPE_AGENT);
    if (__all(xv != 0)) break;
    __builtin_amdgcn_s_sleep(2);
    if (++hb > (1<<16)) break;
  }
  int xv0 = __builtin_amdgcn_readfirstlane(xv);
  bool fastp = __all(xv != 0 && xv == xv0) != 0;

  // ---- stage 2: nt-visibility probe (plain store -> nt load) ----
  int ntok = 0;
  if (fastp){
    if (tid == 0)
      __hip_atomic_store(&xmap[512 + gg*32 + r], r + 1, __ATOMIC_RELAXED, __HIP_MEMORY_SCOPE_WORKGROUP);
    if (w == 0){
      asm volatile("s_waitcnt vmcnt(0)" ::: "memory");
      int tries = 0;
      for (;;){
        asm volatile("" ::: "memory");
        int pv = __builtin_nontemporal_load(&xmap[512 + gg*32 + (lane & 31)]);
        if (__all(pv != 0)){ ntok = 1; break; }
        __builtin_amdgcn_s_sleep(1);
        if (++tries > 2048) break;
      }
    }
  }
  // ---- stage 3: group consensus vote (agent atomics, always works) ----
  if (tid == 0)
    __hip_atomic_store(&xmap[1024 + gg*32 + r], ntok ? 2 : 1, __ATOMIC_RELAXED, __HIP_MEMORY_SCOPE_AGENT);
  if (w == 0){
    int allfast = 0, vb = 0;
    for (;;){
      int v = __hip_atomic_load(&xmap[1024 + gg*32 + (lane & 31)], __ATOMIC_RELAXED, __HIP_MEMORY_SCOPE_AGENT);
      if (__all(v != 0)){ allfast = (__all(v == 2) ? 1 : 0); break; }
      __builtin_amdgcn_s_sleep(2);
      if (++vb > (1<<18)){ allfast = 0; break; }
    }
    if (tid == 0) s_mode = allfast;
  }
  __syncthreads();
  bool dpoll = (s_mode != 0);   // implies fastp

  // gate ownership (waves 0-1 only): rl = tid&7 (local row), cl = tid>>3
  int rl = tid & 7, cl = (tid >> 3) & 15;
  int R = odd*8 + rl;
  int rw = (lane >> 4)*4, cw = lane & 15;
  float c = 0.f, s1 = 0.f, s2 = 0.f;

  int kt_w = r >> 1;
  int kk = (r & 1)*16 + cl;
  int sl_w = rl + 8*(kk >> 3);
  size_t du_off = (((size_t)(gg*16 + kt_w)*32 + sl_w)*8 + (kk & 7)) >> 1;
  int* myflag = flags + (gg*32 + r)*16 + w;
  const int* fwp = flags + (gg*32 + 8*w + ((lane & 15) >> 1))*16 + (lane & 1);

  int sl_r = (lane & 7) + 8*(lane >> 4);

  const s16x8* xv8 = (const s16x8*)xin;
  const s16x8* hvr = (const s16x8*)hex;
  unsigned int* hvw = (unsigned int*)hex;

  // prefetch x fragments for t=0
  s16x8 xa[4];
  if (LAYER == 1){
    const s16x8* ax = xv8 + (q*16 + 4*w)*64 + lane;
#pragma unroll
    for (int i = 0; i < 4; i++) xa[i] = ax[i*64];
  } else {
    const s16x8* ax = xv8 + (size_t)gg*512 + (4*w)*32 + sl_r;
#pragma unroll
    for (int i = 0; i < 4; i++) xa[i] = ax[i*32];
  }

  for (int t = 0; t < T_STEPS; t++){
    // ---- speculative first poll: issue h(t-1) loads BEFORE the X-phase ----
    const u32x4* ap = (const u32x4*)(hvr + ((size_t)(t-1)*16 + gg)*512 + (4*w)*32 + sl_r);
    u32x4 f0, f1, f2, f3;
    bool spec = (t > 0) && dpoll;
    if (spec){
      f0 = __builtin_nontemporal_load(ap);
      f1 = __builtin_nontemporal_load(ap + 32);
      f2 = __builtin_nontemporal_load(ap + 64);
      f3 = __builtin_nontemporal_load(ap + 96);
    }

    f32x4 acc[4];
#pragma unroll
    for (int n = 0; n < 4; n++) acc[n] = (f32x4){0.f,0.f,0.f,0.f};
    // X phase (register-only; speculative loads fly underneath)
#pragma unroll
    for (int ki = 0; ki < 4; ki++)
#pragma unroll
      for (int n = 0; n < 4; n++)
        acc[n] = __builtin_amdgcn_mfma_f32_16x16x32_bf16(xa[ki], B[ki][n], acc[n], 0,0,0);

    if (t > 0){
      s16x8 h0, h1, h2, h3;
      if (dpoll){
        // ---- validate chunks 0/1 (re-poll if sentinel) ----
        {
          int bail = 0;
          for (;;){
            bool ok = true;
#pragma unroll
            for (int i = 0; i < 4; i++)
              ok = ok && (f0[i] != SENT) && (f1[i] != SENT);
            if (__all(ok)) break;
            if (++bail > (1<<12)) break;   // bounded: fail visibly, never hang
            asm volatile("" ::: "memory");
            f0 = __builtin_nontemporal_load(ap);
            f1 = __builtin_nontemporal_load(ap + 32);
          }
        }
        h0 = as_frag(f0); h1 = as_frag(f1);
#pragma unroll
        for (int n = 0; n < 4; n++) acc[n] = __builtin_amdgcn_mfma_f32_16x16x32_bf16(h0, B[4][n], acc[n], 0,0,0);
#pragma unroll
        for (int n = 0; n < 4; n++) acc[n] = __builtin_amdgcn_mfma_f32_16x16x32_bf16(h1, B[5][n], acc[n], 0,0,0);
        // ---- validate chunks 2/3 ----
        {
          int bail = 0;
          for (;;){
            bool ok = true;
#pragma unroll
            for (int i = 0; i < 4; i++)
              ok = ok && (f2[i] != SENT) && (f3[i] != SENT);
            if (__all(ok)) break;
            if (++bail > (1<<12)) break;
            asm volatile("" ::: "memory");
            f2 = __builtin_nontemporal_load(ap + 64);
            f3 = __builtin_nontemporal_load(ap + 96);
          }
        }
        h2 = as_frag(f2); h3 = as_frag(f3);
      } else {
        // ---- round-8 flag path ----
        int bail = 0;
        for (;;){
          int f = __hip_atomic_load(fwp, __ATOMIC_RELAXED, __HIP_MEMORY_SCOPE_AGENT);
          if (__all(f >= t)) break;
          __builtin_amdgcn_s_sleep(2);
          if (++bail > (1<<14)) break;
        }
        asm volatile("" ::: "memory");
        const s16x8* ah = hvr + ((size_t)(t-1)*16 + gg)*512 + (4*w)*32 + sl_r;
        h0 = ah[0]; h1 = ah[32]; h2 = ah[64]; h3 = ah[96];
#pragma unroll
        for (int n = 0; n < 4; n++) acc[n] = __builtin_amdgcn_mfma_f32_16x16x32_bf16(h0, B[4][n], acc[n], 0,0,0);
#pragma unroll
        for (int n = 0; n < 4; n++) acc[n] = __builtin_amdgcn_mfma_f32_16x16x32_bf16(h1, B[5][n], acc[n], 0,0,0);
      }
      // x-prefetch for t+1 AFTER all validation (off the polls' vmcnt waits)
      if (t + 1 < T_STEPS){
        if (LAYER == 1){
          const s16x8* ax = xv8 + (size_t)(t+1)*8192 + (q*16 + 4*w)*64 + lane;
#pragma unroll
          for (int i = 0; i < 4; i++) xa[i] = ax[i*64];
        } else {
          const s16x8* ax = xv8 + ((size_t)(t+1)*16 + gg)*512 + (4*w)*32 + sl_r;
#pragma unroll
          for (int i = 0; i < 4; i++) xa[i] = ax[i*32];
        }
      }
#pragma unroll
      for (int n = 0; n < 4; n++) acc[n] = __builtin_amdgcn_mfma_f32_16x16x32_bf16(h2, B[6][n], acc[n], 0,0,0);
#pragma unroll
      for (int n = 0; n < 4; n++) acc[n] = __builtin_amdgcn_mfma_f32_16x16x32_bf16(h3, B[7][n], acc[n], 0,0,0);
    } else {
      if (t + 1 < T_STEPS){
        if (LAYER == 1){
          const s16x8* ax = xv8 + (size_t)(t+1)*8192 + (q*16 + 4*w)*64 + lane;
#pragma unroll
          for (int i = 0; i < 4; i++) xa[i] = ax[i*64];
        } else {
          const s16x8* ax = xv8 + ((size_t)(t+1)*16 + gg)*512 + (4*w)*32 + sl_r;
#pragma unroll
          for (int i = 0; i < 4; i++) xa[i] = ax[i*32];
        }
      }
    }
    // zone stores (double-buffered; pitch 20 floats)
    float* zb = zs[t & 1];
#pragma unroll
    for (int n = 0; n < 4; n++)
      *(f32x4*)&zb[(w*64 + n*16 + cw)*20 + rw] = acc[n];
    __syncthreads();
    // gate math + publish: waves 0-1, thread owns (row R, hcol = r*16+cl)
    if (tid < 128){
      float z4[4];
#pragma unroll
      for (int n = 0; n < 4; n++){
        z4[n] = zb[(      n*16 + cl)*20 + R]
              + zb[( 64 + n*16 + cl)*20 + R]
              + zb[(128 + n*16 + cl)*20 + R]
              + zb[(192 + n*16 + cl)*20 + R]
              + blds[n*16 + cl];
      }
      float gi = fsig(z4[0]), gf = fsig(z4[1]), gg2 = ftanh(z4[2]), go = fsig(z4[3]);
      c = gf*c + gi*gg2;
      float h = go * ftanh(c);
      if (LAYER == 1){ s1 += h; s2 += h*h; }
      if (LAYER == 2 && t == T_STEPS-1) aux[(size_t)(gg*8 + rl)*512 + r*16 + cl] = h;
      unsigned hv = f2bf(h);
      unsigned other = (unsigned)__shfl_down((int)hv, 8);
      if ((lane & 8) == 0){
        unsigned w32v = hv | (other << 16);
        unsigned int* dst = hvw + (size_t)t*(TS_US/2) + du_off;
        if (fastp) *dst = w32v;        // fire-and-forget; dword self-validates
        else __hip_atomic_store(dst, w32v, __ATOMIC_RELAXED, __HIP_MEMORY_SCOPE_AGENT);
      }
    }
    if (!dpoll){
      asm volatile("s_waitcnt vmcnt(0)" ::: "memory");
      if (w < 2 && lane == 0)
        __hip_atomic_store(myflag, t+1, __ATOMIC_RELAXED, __HIP_MEMORY_SCOPE_AGENT);
    }
  }

  if (LAYER == 1 && tid < 128){
    s1 += __shfl_down(s1, 4); s2 += __shfl_down(s2, 4);
    s1 += __shfl_down(s1, 2); s2 += __shfl_down(s2, 2);
    s1 += __shfl_down(s1, 1); s2 += __shfl_down(s2, 1);
    if ((tid & 7) == 0){
      int ch = r*16 + cl;
      aux[(ch*16 + gg)*2]     = s1;
      aux[(ch*16 + gg)*2 + 1] = s2;
    }
  }
}

// ---------- BN2 + dense head ----------
__global__ __launch_bounds__(512)
void k_epilogue(const float* __restrict__ h2,
                const float* __restrict__ g2, const float* __restrict__ be2,
                const float* __restrict__ Wd1, const float* __restrict__ bd1,
                const float* __restrict__ Wd2, const float* __restrict__ bd2,
                float* __restrict__ out){
  __shared__ float mu[512], rs[512], bb[512];
  __shared__ float t16[128*16];
  int tid = threadIdx.x;
  {
    float s = 0.f, qq = 0.f;
    for (int r = 0; r < 128; r++){ float v = h2[r*512 + tid]; s += v; qq += v*v; }
    float m = s * (1.f/128.f);
    float var = qq * (1.f/128.f) - m*m;
    mu[tid] = m;
    rs[tid] = rsqrtf(fmaxf(var,0.f) + 1e-5f) * g2[tid];
    bb[tid] = be2[tid];
  }
  __syncthreads();
  for (int task = tid; task < 2048; task += 512){
    int b = task >> 4, u = task & 15;
    float acc = bd1[u];
    for (int k = 0; k < 512; k++){
      float hn = (h2[b*512 + k] - mu[k]) * rs[k] + bb[k];
      acc += hn * Wd1[k*16 + u];
    }
    t16[task] = tanhf(acc);
  }
  __syncthreads();
  if (tid < 128){
    float acc = bd2[0];
#pragma unroll
    for (int u = 0; u < 16; u++) acc += t16[tid*16 + u] * Wd2[u];
    out[tid] = acc;
  }
}

extern "C" void kernel_launch(void* const* d_in, const int* in_sizes, int n_in,
                              void* d_out, int out_size, void* d_ws, size_t ws_size,
                              hipStream_t stream){
  const float* x    = (const float*)d_in[0];
  const float* Wi1  = (const float*)d_in[1];
  const float* Wh1  = (const float*)d_in[2];
  const float* b1   = (const float*)d_in[3];
  const float* Wi2  = (const float*)d_in[4];
  const float* Wh2  = (const float*)d_in[5];
  const float* b2   = (const float*)d_in[6];
  const float* g1   = (const float*)d_in[7];
  const float* be1  = (const float*)d_in[8];
  const float* g2   = (const float*)d_in[9];
  const float* be2  = (const float*)d_in[10];
  const float* Wd1  = (const float*)d_in[11];
  const float* bd1  = (const float*)d_in[12];
  const float* Wd2  = (const float*)d_in[13];
  const float* bd2  = (const float*)d_in[14];
  float* out = (float*)d_out;

  char* ws = (char*)d_ws;
  size_t off = 0;
  auto alloc = [&](size_t bytes)->void*{
    void* pp = ws + off; off += (bytes + 255) & ~(size_t)255; return pp;
  };
  unsigned short* xpacked = (unsigned short*)alloc((size_t)512*TS_US*2);  // 64 MiB
  unsigned short* S       = (unsigned short*)alloc((size_t)514*TS_US*2);  // 64.25 MiB
  unsigned short* w1p     = (unsigned short*)alloc((size_t)32*128*64*8*2);
  unsigned short* w2p     = (unsigned short*)alloc((size_t)32*128*64*8*2);
  float* bias1  = (float*)alloc(2048*4);
  float* bias2  = (float*)alloc(2048*4);
  float* stats1 = (float*)alloc((size_t)512*16*2*4);
  int*   flags1 = (int*)alloc(8192*4);
  int*   flags2 = (int*)alloc(8192*4);
  int*   xmap1  = (int*)alloc(2048*4);
  int*   xmap2  = (int*)alloc(2048*4);
  float* h2last = (float*)alloc((size_t)128*512*4);

  if (off > ws_size){
    k_sentinel<<<1, 256, 0, stream>>>(out, out_size, (float)(ws_size >> 20));
    return;
  }

  unsigned short* S2 = S + (size_t)2*TS_US;

  k_reset<<<1, 1024, 0, stream>>>(flags1, flags2, xmap1, xmap2);
  // NaN-fill layer-1's h-exchange buffer (write-once slots; data-poll detect)
  k_fill<<<2048, 256, 0, stream>>>((unsigned int*)S, (long)514*TS_US/8);
  k_pack_x<<<4096, 256, 0, stream>>>(x, xpacked);
  k_pack_w1<<<32, 256, 0, stream>>>(Wi1, Wh1, b1, w1p, bias1);
  k_scan<1><<<512, 256, 0, stream>>>(xpacked, S2, w1p, bias1, flags1, xmap1, stats1);
  k_fold2<<<32, 256, 0, stream>>>(Wi2, Wh2, b2, g1, be1, stats1, w2p, bias2);
  // NaN-fill layer-2's h-exchange buffer (xpacked reused; scan1 has fully read it)
  k_fill<<<2048, 256, 0, stream>>>((unsigned int*)xpacked, (long)512*TS_US/8);
  k_scan<2><<<512, 256, 0, stream>>>(S2, xpacked, w2p, bias2, flags2, xmap2, h2last);
  k_epilogue<<<1, 512, 0, stream>>>(h2last, g2, be2, Wd1, bd1, Wd2, bd2, out);
}

// Round 13
// 2001.001 us; speedup vs baseline: 1.7980x; 1.0926x over previous
//
#include <hip/hip_runtime.h>
#include <hip/hip_bf16.h>

#define T_STEPS 512
#define TS_US   65536         // ushorts per t-slot (128KB) for x and h buffers
#define SENT    0x7FC07FC0u   // bf16 NaN pair: h can never equal this

typedef __attribute__((ext_vector_type(4))) float f32x4;
typedef __attribute__((ext_vector_type(8))) short s16x8;
typedef __attribute__((ext_vector_type(4))) unsigned int u32x4;

// ---------- helpers ----------
__device__ __forceinline__ unsigned short f2bf(float f){
  unsigned int u = __float_as_uint(f);
  unsigned int r = (u + 0x7fffu + ((u >> 16) & 1u)) >> 16;
  return (unsigned short)r;
}
__device__ __forceinline__ float fsig(float x){
  return __builtin_amdgcn_rcpf(1.f + __expf(-x));
}
__device__ __forceinline__ float ftanh(float x){
  x = fminf(fmaxf(x, -15.f), 15.f);
  float a = __expf(2.f * x);
  return (a - 1.f) * __builtin_amdgcn_rcpf(a + 1.f);
}
__device__ __forceinline__ s16x8 as_frag(u32x4 v){
  union { u32x4 u; s16x8 s; } c; c.u = v; return c.s;
}

// ---------- pack x into 16-row (q-group) MFMA A-fragment layout ----------
__global__ void k_pack_x(const float* __restrict__ x, unsigned short* __restrict__ xp){
  int t = blockIdx.x >> 3, q = blockIdx.x & 7;
  __shared__ unsigned short xs[16*520];
  int tid = threadIdx.x;
  for (int qq = tid; qq < 1024; qq += 256){
    int rw = qq >> 6, k8 = qq & 63;
    const float* src = x + ((size_t)(q*16 + rw)*512 + t)*512 + k8*8;
    union { unsigned short u[8]; s16x8 v; } tmp;
#pragma unroll
    for (int e = 0; e < 8; e++) tmp.u[e] = f2bf(src[e]);
    *(s16x8*)&xs[rw*520 + k8*8] = tmp.v;
  }
  __syncthreads();
  for (int s = tid; s < 1024; s += 256){
    int kt = s >> 6, ln = s & 63;
    int rw2 = ln & 15, k0 = kt*32 + (ln >> 4)*8;
    s16x8 v = *(const s16x8*)&xs[rw2*520 + k0];
    ((s16x8*)xp)[(size_t)t*8192 + (q*16 + kt)*64 + ln] = v;
  }
}

// ---------- pack layer-1 weights into B-fragment layout ----------
__global__ void k_pack_w1(const float* __restrict__ Wi, const float* __restrict__ Wh,
                          const float* __restrict__ b, unsigned short* __restrict__ wp,
                          float* __restrict__ bias){
  int r = blockIdx.x, tid = threadIdx.x;
  int lane = tid & 63, u0 = tid >> 6;
  for (int ch = u0; ch < 128; ch += 4){
    int kt = ch >> 2, n = ch & 3;
    int col = n*512 + r*16 + (lane & 15);
    int kb = kt*32 + (lane >> 4)*8;
    union { unsigned short u[8]; s16x8 v; } tmp;
#pragma unroll
    for (int e = 0; e < 8; e++){
      int k = kb + e;
      float wv = (kt < 16) ? Wi[(size_t)k*2048 + col] : Wh[(size_t)(k-512)*2048 + col];
      tmp.u[e] = f2bf(wv);
    }
    ((s16x8*)wp)[((size_t)r*128 + ch)*64 + lane] = tmp.v;
  }
  if (tid < 64) bias[r*64 + tid] = b[(tid >> 4)*512 + r*16 + (tid & 15)];
}

// ---------- fold BN1 into Wi2, pack layer-2 weights, fused bias ----------
__global__ void k_fold2(const float* __restrict__ Wi2, const float* __restrict__ Wh2,
                        const float* __restrict__ b2, const float* __restrict__ gamma,
                        const float* __restrict__ beta, const float* __restrict__ stats,
                        unsigned short* __restrict__ wp, float* __restrict__ bias){
  __shared__ float a_s[512], c_s[512], red[256];
  int r = blockIdx.x, tid = threadIdx.x;
  for (int k = tid; k < 512; k += 256){
    float sm = 0.f, sq = 0.f;
#pragma unroll
    for (int g = 0; g < 16; g++){ sm += stats[(k*16+g)*2]; sq += stats[(k*16+g)*2+1]; }
    float mean = sm * (1.f/65536.f);
    float var  = sq * (1.f/65536.f) - mean*mean;
    float rr = rsqrtf(fmaxf(var, 0.f) + 1e-5f);
    float a = rr * gamma[k];
    a_s[k] = a; c_s[k] = beta[k] - mean*a;
  }
  __syncthreads();
  int lane = tid & 63, u0 = tid >> 6;
  for (int ch = u0; ch < 128; ch += 4){
    int kt = ch >> 2, n = ch & 3;
    int col = n*512 + r*16 + (lane & 15);
    int kb = kt*32 + (lane >> 4)*8;
    union { unsigned short u[8]; s16x8 v; } tmp;
#pragma unroll
    for (int e = 0; e < 8; e++){
      int k = kb + e;
      float wv = (kt < 16) ? a_s[k]*Wi2[(size_t)k*2048 + col]
                           : Wh2[(size_t)(k-512)*2048 + col];
      tmp.u[e] = f2bf(wv);
    }
    ((s16x8*)wp)[((size_t)r*128 + ch)*64 + lane] = tmp.v;
  }
  int colj = tid >> 2, part = tid & 3;
  int n = colj >> 4, cl = colj & 15;
  int col = n*512 + r*16 + cl;
  float s = 0.f;
  for (int k = part*128; k < part*128 + 128; k++) s += c_s[k]*Wi2[(size_t)k*2048 + col];
  red[tid] = s;
  __syncthreads();
  if (part == 0)
    bias[r*64 + colj] = b2[col] + red[tid] + red[tid+1] + red[tid+2] + red[tid+3];
}

__global__ void k_reset(int* f1, int* f2, int* x1, int* x2){
  int t = threadIdx.x;
  for (int i = t; i < 8192; i += 1024){ f1[i] = 0; f2[i] = 0; }
  for (int i = t; i < 2048; i += 1024){ x1[i] = 0; x2[i] = 0; }
}

// fill a region with the bf16-NaN sentinel (n in uint4 units)
__global__ void k_fill(unsigned int* __restrict__ p, long n){
  u32x4 v = {SENT, SENT, SENT, SENT};
  u32x4* q = (u32x4*)p;
  long i = (long)blockIdx.x*blockDim.x + threadIdx.x;
  long stride = (long)gridDim.x*blockDim.x;
  for (; i < n; i += stride) q[i] = v;
}

__global__ void k_sentinel(float* out, int n, float v){
  int i = blockIdx.x * blockDim.x + threadIdx.x;
  if (i < n) out[i] = v;
}

// ---------- persistent group-local LSTM scan (round-9 best configuration) ----
// 512 blocks x 256 threads. 16 groups x 8 batch rows; gg = blockIdx&15,
// r = blockIdx>>4 (group's 32 ranks share one XCD; 2 groups/XCD, 2 blocks/CU).
// DATAPOLL mode (fastp + nt-probe + group consensus): h-exchange slots are
// write-once and pre-filled with bf16-NaN sentinel; consumers poll the h DATA
// itself with nt-loads (L1-bypass) and use the loaded values directly.
// Publish is fire-and-forget dword stores (each dword self-validates).
// Fallback (probe/vote fails): round-8 flag mechanism, bit-exact.
// x-prefetch issued AFTER detect so the poll never waits on it.
template<int LAYER>
__global__ __launch_bounds__(256, 2)
void k_scan(const unsigned short* __restrict__ xin, unsigned short* __restrict__ hex,
            const unsigned short* __restrict__ wp, const float* __restrict__ bias,
            int* __restrict__ flags, int* __restrict__ xmap, float* __restrict__ aux){
  __shared__ __align__(16) float zs[2][4*64*20];
  __shared__ float blds[64];
  __shared__ int s_mode;
  int gg = blockIdx.x & 15, r = blockIdx.x >> 4;
  int q = gg >> 1, odd = gg & 1;
  int tid = threadIdx.x, w = tid >> 6, lane = tid & 63;

  // weight fragments -> registers/AGPRs (volatile: load exactly once)
  const volatile s16x8* wpv = (const volatile s16x8*)((const s16x8*)wp + (size_t)r*128*64);
  s16x8 B[8][4];
#pragma unroll
  for (int ki = 0; ki < 8; ki++){
    int kt = (ki < 4) ? (4*w + ki) : (12 + 4*w + ki);
#pragma unroll
    for (int n = 0; n < 4; n++)
      B[ki][n] = wpv[((size_t)kt*4 + n)*64 + lane];
  }
  if (tid < 64) blds[tid] = bias[r*64 + tid];

  // ---- stage 1: XCD uniformity handshake ----
  int myx;
  asm volatile("s_getreg_b32 %0, hwreg(HW_REG_XCC_ID)" : "=s"(myx));
  if (tid == 0)
    __hip_atomic_store(&xmap[gg*32 + r], (myx & 0xff) + 1, __ATOMIC_RELAXED, __HIP_MEMORY_SCOPE_AGENT);
  int xv, hb = 0;
  for (;;){
    xv = __hip_atomic_load(&xmap[gg*32 + (lane & 31)], __ATOMIC_RELAXED, __HIP_MEMORY_SCOPE_AGENT);
    if (__all(xv != 0)) break;
    __builtin_amdgcn_s_sleep(2);
    if (++hb > (1<<16)) break;
  }
  int xv0 = __builtin_amdgcn_readfirstlane(xv);
  bool fastp = __all(xv != 0 && xv == xv0) != 0;

  // ---- stage 2: nt-visibility probe (plain store -> nt load) ----
  int ntok = 0;
  if (fastp){
    if (tid == 0)
      __hip_atomic_store(&xmap[512 + gg*32 + r], r + 1, __ATOMIC_RELAXED, __HIP_MEMORY_SCOPE_WORKGROUP);
    if (w == 0){
      asm volatile("s_waitcnt vmcnt(0)" ::: "memory");
      int tries = 0;
      for (;;){
        asm volatile("" ::: "memory");
        int pv = __builtin_nontemporal_load(&xmap[512 + gg*32 + (lane & 31)]);
        if (__all(pv != 0)){ ntok = 1; break; }
        __builtin_amdgcn_s_sleep(1);
        if (++tries > 2048) break;
      }
    }
  }
  // ---- stage 3: group consensus vote (agent atomics, always works) ----
  if (tid == 0)
    __hip_atomic_store(&xmap[1024 + gg*32 + r], ntok ? 2 : 1, __ATOMIC_RELAXED, __HIP_MEMORY_SCOPE_AGENT);
  if (w == 0){
    int allfast = 0, vb = 0;
    for (;;){
      int v = __hip_atomic_load(&xmap[1024 + gg*32 + (lane & 31)], __ATOMIC_RELAXED, __HIP_MEMORY_SCOPE_AGENT);
      if (__all(v != 0)){ allfast = (__all(v == 2) ? 1 : 0); break; }
      __builtin_amdgcn_s_sleep(2);
      if (++vb > (1<<18)){ allfast = 0; break; }
    }
    if (tid == 0) s_mode = allfast;
  }
  __syncthreads();
  bool dpoll = (s_mode != 0);   // implies fastp

  // gate ownership (waves 0-1 only): rl = tid&7 (local row), cl = tid>>3
  int rl = tid & 7, cl = (tid >> 3) & 15;
  int R = odd*8 + rl;
  int rw = (lane >> 4)*4, cw = lane & 15;
  float c = 0.f, s1 = 0.f, s2 = 0.f;

  int kt_w = r >> 1;
  int kk = (r & 1)*16 + cl;
  int sl_w = rl + 8*(kk >> 3);
  size_t du_off = (((size_t)(gg*16 + kt_w)*32 + sl_w)*8 + (kk & 7)) >> 1;
  int* myflag = flags + (gg*32 + r)*16 + w;
  const int* fwp = flags + (gg*32 + 8*w + ((lane & 15) >> 1))*16 + (lane & 1);

  int sl_r = (lane & 7) + 8*(lane >> 4);

  const s16x8* xv8 = (const s16x8*)xin;
  const s16x8* hvr = (const s16x8*)hex;
  unsigned int* hvw = (unsigned int*)hex;

  // prefetch x fragments for t=0
  s16x8 xa[4];
  if (LAYER == 1){
    const s16x8* ax = xv8 + (q*16 + 4*w)*64 + lane;
#pragma unroll
    for (int i = 0; i < 4; i++) xa[i] = ax[i*64];
  } else {
    const s16x8* ax = xv8 + (size_t)gg*512 + (4*w)*32 + sl_r;
#pragma unroll
    for (int i = 0; i < 4; i++) xa[i] = ax[i*32];
  }

  for (int t = 0; t < T_STEPS; t++){
    f32x4 acc[4];
#pragma unroll
    for (int n = 0; n < 4; n++) acc[n] = (f32x4){0.f,0.f,0.f,0.f};
    // X phase (independent of recurrence)
#pragma unroll
    for (int ki = 0; ki < 4; ki++)
#pragma unroll
      for (int n = 0; n < 4; n++)
        acc[n] = __builtin_amdgcn_mfma_f32_16x16x32_bf16(xa[ki], B[ki][n], acc[n], 0,0,0);

    if (t > 0){
      s16x8 h0, h1, h2, h3;
      if (dpoll){
        // ---- flagless detect: poll the h data itself for non-sentinel ----
        const u32x4* ap = (const u32x4*)(hvr + ((size_t)(t-1)*16 + gg)*512 + (4*w)*32 + sl_r);
        u32x4 f0, f1, f2, f3;
        int bail = 0;
        for (;;){
          asm volatile("" ::: "memory");
          f0 = __builtin_nontemporal_load(ap);
          f1 = __builtin_nontemporal_load(ap + 32);
          f2 = __builtin_nontemporal_load(ap + 64);
          f3 = __builtin_nontemporal_load(ap + 96);
          bool ok = true;
#pragma unroll
          for (int i = 0; i < 4; i++)
            ok = ok && (f0[i] != SENT) && (f1[i] != SENT) && (f2[i] != SENT) && (f3[i] != SENT);
          if (__all(ok)) break;
          if (++bail > (1<<12)) break;   // bounded: fail visibly, never hang
        }
        h0 = as_frag(f0); h1 = as_frag(f1); h2 = as_frag(f2); h3 = as_frag(f3);
      } else {
        // ---- round-8 flag path ----
        int bail = 0;
        for (;;){
          int f = __hip_atomic_load(fwp, __ATOMIC_RELAXED, __HIP_MEMORY_SCOPE_AGENT);
          if (__all(f >= t)) break;
          __builtin_amdgcn_s_sleep(2);
          if (++bail > (1<<14)) break;
        }
        asm volatile("" ::: "memory");
        const s16x8* ah = hvr + ((size_t)(t-1)*16 + gg)*512 + (4*w)*32 + sl_r;
        h0 = ah[0]; h1 = ah[32]; h2 = ah[64]; h3 = ah[96];
      }
      // x-prefetch for t+1 AFTER detect (off the poll's vmcnt drain)
      if (t + 1 < T_STEPS){
        if (LAYER == 1){
          const s16x8* ax = xv8 + (size_t)(t+1)*8192 + (q*16 + 4*w)*64 + lane;
#pragma unroll
          for (int i = 0; i < 4; i++) xa[i] = ax[i*64];
        } else {
          const s16x8* ax = xv8 + ((size_t)(t+1)*16 + gg)*512 + (4*w)*32 + sl_r;
#pragma unroll
          for (int i = 0; i < 4; i++) xa[i] = ax[i*32];
        }
      }
#pragma unroll
      for (int n = 0; n < 4; n++) acc[n] = __builtin_amdgcn_mfma_f32_16x16x32_bf16(h0, B[4][n], acc[n], 0,0,0);
#pragma unroll
      for (int n = 0; n < 4; n++) acc[n] = __builtin_amdgcn_mfma_f32_16x16x32_bf16(h1, B[5][n], acc[n], 0,0,0);
#pragma unroll
      for (int n = 0; n < 4; n++) acc[n] = __builtin_amdgcn_mfma_f32_16x16x32_bf16(h2, B[6][n], acc[n], 0,0,0);
#pragma unroll
      for (int n = 0; n < 4; n++) acc[n] = __builtin_amdgcn_mfma_f32_16x16x32_bf16(h3, B[7][n], acc[n], 0,0,0);
    } else {
      if (t + 1 < T_STEPS){
        if (LAYER == 1){
          const s16x8* ax = xv8 + (size_t)(t+1)*8192 + (q*16 + 4*w)*64 + lane;
#pragma unroll
          for (int i = 0; i < 4; i++) xa[i] = ax[i*64];
        } else {
          const s16x8* ax = xv8 + ((size_t)(t+1)*16 + gg)*512 + (4*w)*32 + sl_r;
#pragma unroll
          for (int i = 0; i < 4; i++) xa[i] = ax[i*32];
        }
      }
    }
    // zone stores (double-buffered; pitch 20 floats)
    float* zb = zs[t & 1];
#pragma unroll
    for (int n = 0; n < 4; n++)
      *(f32x4*)&zb[(w*64 + n*16 + cw)*20 + rw] = acc[n];
    __syncthreads();
    // gate math + publish: waves 0-1, thread owns (row R, hcol = r*16+cl)
    if (tid < 128){
      float z4[4];
#pragma unroll
      for (int n = 0; n < 4; n++){
        z4[n] = zb[(      n*16 + cl)*20 + R]
              + zb[( 64 + n*16 + cl)*20 + R]
              + zb[(128 + n*16 + cl)*20 + R]
              + zb[(192 + n*16 + cl)*20 + R]
              + blds[n*16 + cl];
      }
      float gi = fsig(z4[0]), gf = fsig(z4[1]), gg2 = ftanh(z4[2]), go = fsig(z4[3]);
      c = gf*c + gi*gg2;
      float h = go * ftanh(c);
      if (LAYER == 1){ s1 += h; s2 += h*h; }
      if (LAYER == 2 && t == T_STEPS-1) aux[(size_t)(gg*8 + rl)*512 + r*16 + cl] = h;
      unsigned hv = f2bf(h);
      unsigned other = (unsigned)__shfl_down((int)hv, 8);
      if ((lane & 8) == 0){
        unsigned w32v = hv | (other << 16);
        unsigned int* dst = hvw + (size_t)t*(TS_US/2) + du_off;
        if (fastp) *dst = w32v;        // fire-and-forget; dword self-validates
        else __hip_atomic_store(dst, w32v, __ATOMIC_RELAXED, __HIP_MEMORY_SCOPE_AGENT);
      }
    }
    if (!dpoll){
      asm volatile("s_waitcnt vmcnt(0)" ::: "memory");
      if (w < 2 && lane == 0)
        __hip_atomic_store(myflag, t+1, __ATOMIC_RELAXED, __HIP_MEMORY_SCOPE_AGENT);
    }
  }

  if (LAYER == 1 && tid < 128){
    s1 += __shfl_down(s1, 4); s2 += __shfl_down(s2, 4);
    s1 += __shfl_down(s1, 2); s2 += __shfl_down(s2, 2);
    s1 += __shfl_down(s1, 1); s2 += __shfl_down(s2, 1);
    if ((tid & 7) == 0){
      int ch = r*16 + cl;
      aux[(ch*16 + gg)*2]     = s1;
      aux[(ch*16 + gg)*2 + 1] = s2;
    }
  }
}

// ---------- BN2 + dense head ----------
__global__ __launch_bounds__(512)
void k_epilogue(const float* __restrict__ h2,
                const float* __restrict__ g2, const float* __restrict__ be2,
                const float* __restrict__ Wd1, const float* __restrict__ bd1,
                const float* __restrict__ Wd2, const float* __restrict__ bd2,
                float* __restrict__ out){
  __shared__ float mu[512], rs[512], bb[512];
  __shared__ float t16[128*16];
  int tid = threadIdx.x;
  {
    float s = 0.f, qq = 0.f;
    for (int r = 0; r < 128; r++){ float v = h2[r*512 + tid]; s += v; qq += v*v; }
    float m = s * (1.f/128.f);
    float var = qq * (1.f/128.f) - m*m;
    mu[tid] = m;
    rs[tid] = rsqrtf(fmaxf(var,0.f) + 1e-5f) * g2[tid];
    bb[tid] = be2[tid];
  }
  __syncthreads();
  for (int task = tid; task < 2048; task += 512){
    int b = task >> 4, u = task & 15;
    float acc = bd1[u];
    for (int k = 0; k < 512; k++){
      float hn = (h2[b*512 + k] - mu[k]) * rs[k] + bb[k];
      acc += hn * Wd1[k*16 + u];
    }
    t16[task] = tanhf(acc);
  }
  __syncthreads();
  if (tid < 128){
    float acc = bd2[0];
#pragma unroll
    for (int u = 0; u < 16; u++) acc += t16[tid*16 + u] * Wd2[u];
    out[tid] = acc;
  }
}

extern "C" void kernel_launch(void* const* d_in, const int* in_sizes, int n_in,
                              void* d_out, int out_size, void* d_ws, size_t ws_size,
                              hipStream_t stream){
  const float* x    = (const float*)d_in[0];
  const float* Wi1  = (const float*)d_in[1];
  const float* Wh1  = (const float*)d_in[2];
  const float* b1   = (const float*)d_in[3];
  const float* Wi2  = (const float*)d_in[4];
  const float* Wh2  = (const float*)d_in[5];
  const float* b2   = (const float*)d_in[6];
  const float* g1   = (const float*)d_in[7];
  const float* be1  = (const float*)d_in[8];
  const float* g2   = (const float*)d_in[9];
  const float* be2  = (const float*)d_in[10];
  const float* Wd1  = (const float*)d_in[11];
  const float* bd1  = (const float*)d_in[12];
  const float* Wd2  = (const float*)d_in[13];
  const float* bd2  = (const float*)d_in[14];
  float* out = (float*)d_out;

  char* ws = (char*)d_ws;
  size_t off = 0;
  auto alloc = [&](size_t bytes)->void*{
    void* pp = ws + off; off += (bytes + 255) & ~(size_t)255; return pp;
  };
  unsigned short* xpacked = (unsigned short*)alloc((size_t)512*TS_US*2);  // 64 MiB
  unsigned short* S       = (unsigned short*)alloc((size_t)514*TS_US*2);  // 64.25 MiB
  unsigned short* w1p     = (unsigned short*)alloc((size_t)32*128*64*8*2);
  unsigned short* w2p     = (unsigned short*)alloc((size_t)32*128*64*8*2);
  float* bias1  = (float*)alloc(2048*4);
  float* bias2  = (float*)alloc(2048*4);
  float* stats1 = (float*)alloc((size_t)512*16*2*4);
  int*   flags1 = (int*)alloc(8192*4);
  int*   flags2 = (int*)alloc(8192*4);
  int*   xmap1  = (int*)alloc(2048*4);
  int*   xmap2  = (int*)alloc(2048*4);
  float* h2last = (float*)alloc((size_t)128*512*4);

  if (off > ws_size){
    k_sentinel<<<1, 256, 0, stream>>>(out, out_size, (float)(ws_size >> 20));
    return;
  }

  unsigned short* S2 = S + (size_t)2*TS_US;

  k_reset<<<1, 1024, 0, stream>>>(flags1, flags2, xmap1, xmap2);
  // NaN-fill layer-1's h-exchange buffer (write-once slots; data-poll detect)
  k_fill<<<2048, 256, 0, stream>>>((unsigned int*)S, (long)514*TS_US/8);
  k_pack_x<<<4096, 256, 0, stream>>>(x, xpacked);
  k_pack_w1<<<32, 256, 0, stream>>>(Wi1, Wh1, b1, w1p, bias1);
  k_scan<1><<<512, 256, 0, stream>>>(xpacked, S2, w1p, bias1, flags1, xmap1, stats1);
  k_fold2<<<32, 256, 0, stream>>>(Wi2, Wh2, b2, g1, be1, stats1, w2p, bias2);
  // NaN-fill layer-2's h-exchange buffer (xpacked reused; scan1 has fully read it)
  k_fill<<<2048, 256, 0, stream>>>((unsigned int*)xpacked, (long)512*TS_US/8);
  k_scan<2><<<512, 256, 0, stream>>>(S2, xpacked, w2p, bias2, flags2, xmap2, h2last);
  k_epilogue<<<1, 512, 0, stream>>>(h2last, g2, be2, Wd1, bd1, Wd2, bd2, out);
}